// Round 2
// baseline (393.801 us; speedup 1.0000x reference)
//
#include <hip/hip_runtime.h>

// StandardDeviationPooling: 4x4 windows, stride 2, VALID.
// in:  (64, 1024, 1024) fp32   out: (64, 511, 511) fp32
// std = sqrt(max(E[x^2] - E[x]^2, 0)), n = 16.
//
// Design (R2): separable window. Horizontal: pair sums p[i]=x[2i]+x[2i+1],
// output col o = p[o] + p[o+1]. Vertical: row-pair sums P[t]=h[2t]+h[2t+1],
// output row j = P[j] + P[j+1]. Lane l loads ONE contiguous float4 per row
// (wave = 1 KiB dense per VMEM instr), owns output cols {128w+2l, +1}; the
// cross-lane pair comes from __shfl_down(.,1) (DPP, no LDS). A block of 256
// threads (4 waves) covers the full 1024-col width exactly (511 outputs) and
// marches down a 16-output-row strip keeping the previous row-pair sum in
// registers -> each input row read once per strip (2-row overlap per strip).

#define IN_H 1024
#define IN_W 1024
#define OUT_H 511
#define OUT_W 511
#define STRIPS 32
#define ROWS_PER_STRIP 16  // output rows per strip (last strip: 15)

__global__ __launch_bounds__(256, 8) void stdpool_kernel(
    const float* __restrict__ in, float* __restrict__ out) {
  const int tid = threadIdx.x;
  const int w = tid >> 6;  // wave 0..3
  const int l = tid & 63;  // lane 0..63
  const int strip = blockIdx.x;
  const int b = blockIdx.y;

  const int col0 = w * 256 + l * 4;      // first input col this lane loads
  const int o0 = w * 128 + l * 2;        // first output col this lane owns
  const bool has_o1 = (o0 + 1) < OUT_W;  // false only for w==3, l==63
  const bool tail = (l == 63) && has_o1; // needs cols col0+4, col0+5

  const int j0 = strip * ROWS_PER_STRIP;
  const int jn = min(ROWS_PER_STRIP, OUT_H - j0);  // 16 (last strip 15)
  const int t0 = j0, t1 = j0 + jn;  // row-pair indices t0..t1 inclusive

  const float* __restrict__ src = in + (size_t)b * IN_H * IN_W;
  float* __restrict__ dst = out + (size_t)b * OUT_H * OUT_W;

  // preload rowpair t0 (input rows 2*t0, 2*t0+1)
  const float* rp = src + (size_t)(2 * t0) * IN_W + col0;
  float4 a = *(const float4*)rp;
  float4 c = *(const float4*)(rp + IN_W);

  float Pp0 = 0.f, Pp1 = 0.f, Qp0 = 0.f, Qp1 = 0.f;  // previous row-pair sums

  for (int t = t0; t <= t1; ++t) {
    // prefetch next rowpair while computing this one
    float4 na = make_float4(0.f, 0.f, 0.f, 0.f);
    float4 nc = na;
    if (t < t1) {
      const float* np = src + (size_t)(2 * (t + 1)) * IN_W + col0;
      na = *(const float4*)np;
      nc = *(const float4*)(np + IN_W);
    }

    // two-row-combined horizontal pair sums (values and squares)
    float c0 = (a.x + a.y) + (c.x + c.y);
    float c1 = (a.z + a.w) + (c.z + c.w);
    float d0 = fmaf(a.y, a.y, a.x * a.x) + fmaf(c.y, c.y, c.x * c.x);
    float d1 = fmaf(a.w, a.w, a.z * a.z) + fmaf(c.w, c.w, c.z * c.z);

    // neighbor lane's even pair (pair index o0+2 lives in lane l+1)
    float cn = __shfl_down(c0, 1, 64);
    float dn = __shfl_down(d0, 1, 64);
    if (tail) {  // lane 63: pair comes from the next wave's columns
      const float* tp = src + (size_t)(2 * t) * IN_W + col0 + 4;
      const float2 e0 = *(const float2*)tp;
      const float2 e1 = *(const float2*)(tp + IN_W);
      cn = (e0.x + e0.y) + (e1.x + e1.y);
      dn = fmaf(e0.y, e0.y, e0.x * e0.x) + fmaf(e1.y, e1.y, e1.x * e1.x);
    }

    const float P0 = c0 + c1, P1 = c1 + cn;   // row-pair window sums
    const float Q0 = d0 + d1, Q1 = d1 + dn;

    if (t > t0) {  // emit output row t-1 from rowpairs (t-1, t)
      const float inv = 1.0f / 16.0f;
      const float s0 = Pp0 + P0, s1 = Pp1 + P1;
      const float q0 = Qp0 + Q0, q1 = Qp1 + Q1;
      const float m0 = s0 * inv, m1 = s1 * inv;
      const float v0 = fmaxf(fmaf(-m0, m0, q0 * inv), 0.0f);
      const float v1 = fmaxf(fmaf(-m1, m1, q1 * inv), 0.0f);
      float* op = dst + (size_t)(t - 1) * OUT_W + o0;
      op[0] = sqrtf(v0);               // out rows are only 4B-aligned ->
      if (has_o1) op[1] = sqrtf(v1);   // two dword stores, both dense
    }

    Pp0 = P0; Pp1 = P1; Qp0 = Q0; Qp1 = Q1;
    a = na; c = nc;
  }
}

extern "C" void kernel_launch(void* const* d_in, const int* in_sizes, int n_in,
                              void* d_out, int out_size, void* d_ws,
                              size_t ws_size, hipStream_t stream) {
  const float* x = (const float*)d_in[0];
  float* out = (float*)d_out;

  dim3 block(256, 1, 1);
  dim3 grid(STRIPS, 64, 1);  // 32 row-strips x 64 images = 2048 blocks
  stdpool_kernel<<<grid, block, 0, stream>>>(x, out);
}

// Round 3
// 380.454 us; speedup vs baseline: 1.0351x; 1.0351x over previous
//
#include <hip/hip_runtime.h>

// StandardDeviationPooling: 4x4 windows, stride 2, VALID.
// in:  (64, 1024, 1024) fp32   out: (64, 511, 511) fp32
// std = sqrt(max(E[x^2] - E[x]^2, 0)), n = 16.
//
// R3: separable rolling-window streaming kernel.
//  - Horizontal: pair sums p[i]=x[2i]+x[2i+1]; out col o = p[o]+p[o+1].
//  - Vertical:   rowpair sums P[t]=h[2t]+h[2t+1]; out row j = P[j]+P[j+1].
//  - Lane l loads ONE contiguous float4/row (wave = 1 KiB dense per VMEM op),
//    owns output cols {128w+2l, +1}; the cross-lane pair comes from
//    __shfl_down(.,1). Lane 63's cross-wave pair words are PREFETCHED in the
//    same depth-2 pipeline as the main loads (R2 consumed them immediately ->
//    full-latency wave stall every iteration).
//  - __launch_bounds__(256,4): 128-VGPR cap. R2 used (256,8) = 64-VGPR cap,
//    a likely scratch-spill source.
//  - 16 strips of 32 output rows: 1024 blocks = 4/CU resident, 3% overlap.

#define IN_H 1024
#define IN_W 1024
#define OUT_H 511
#define OUT_W 511
#define STRIPS 16
#define ORPS 32            // output rows per strip
#define PAIRS (ORPS + 1)   // rowpairs touched per strip

__global__ __launch_bounds__(256, 4) void stdpool_kernel(
    const float* __restrict__ in, float* __restrict__ out) {
  const int tid = threadIdx.x;
  const int w = tid >> 6;  // wave 0..3
  const int l = tid & 63;  // lane 0..63
  const int strip = blockIdx.x;
  const int b = blockIdx.y;

  const int col0 = w * 256 + l * 4;      // first input col this lane loads
  const int o0 = w * 128 + l * 2;        // first output col this lane owns
  const bool has_o1 = (o0 + 1) < OUT_W;  // false only for w==3, l==63
  const bool tail = (l == 63) && has_o1; // lane 63 needs cols col0+4..5

  const int t0 = strip * ORPS;  // first rowpair index of this strip

  const float* __restrict__ src = in + (size_t)b * IN_H * IN_W + col0;
  float* __restrict__ dst = out + (size_t)b * OUT_H * OUT_W + o0;

  float4 A[2], C[2];   // double-buffered rowpair data (rows 2t, 2t+1)
  float2 E0[2], E1[2]; // lane-63 tail words, same pipeline

  // preload rowpairs t=0,1 (never needs clamping: max row = 2*(480+1)+1)
#pragma unroll
  for (int t = 0; t < 2; ++t) {
    const float* p = src + (size_t)(2 * (t0 + t)) * IN_W;
    A[t] = *(const float4*)p;
    C[t] = *(const float4*)(p + IN_W);
    if (tail) {
      E0[t] = *(const float2*)(p + 4);
      E1[t] = *(const float2*)(p + IN_W + 4);
    }
  }

  float Pp0 = 0.f, Pp1 = 0.f, Qp0 = 0.f, Qp1 = 0.f;

#pragma unroll
  for (int t = 0; t < PAIRS; ++t) {
    const int k = t & 1;
    const float4 a = A[k], c = C[k];
    const float2 e0 = E0[k], e1 = E1[k];

    // prefetch rowpair t+2 into the slot just freed (depth-2 pipeline)
    if (t + 2 < PAIRS) {
      int r = 2 * (t0 + t + 2);
      if (r > IN_H - 2) r = IN_H - 2;  // strip 15 tail: harmless re-read
      const float* p = src + (size_t)r * IN_W;
      A[k] = *(const float4*)p;
      C[k] = *(const float4*)(p + IN_W);
      if (tail) {
        E0[k] = *(const float2*)(p + 4);
        E1[k] = *(const float2*)(p + IN_W + 4);
      }
    }

    // two-row-combined horizontal pair sums (values, squares)
    const float c0 = (a.x + a.y) + (c.x + c.y);
    const float c1 = (a.z + a.w) + (c.z + c.w);
    const float d0 = fmaf(a.x, a.x, a.y * a.y) + fmaf(c.x, c.x, c.y * c.y);
    const float d1 = fmaf(a.z, a.z, a.w * a.w) + fmaf(c.z, c.z, c.w * c.w);

    // neighbor lane's even pair (pair o0+2 lives in lane l+1)
    float cn = __shfl_down(c0, 1, 64);
    float dn = __shfl_down(d0, 1, 64);
    if (tail) {  // lane 63: pair comes from the next wave's columns
      cn = (e0.x + e0.y) + (e1.x + e1.y);
      dn = fmaf(e0.x, e0.x, e0.y * e0.y) + fmaf(e1.x, e1.x, e1.y * e1.y);
    }

    const float P0 = c0 + c1, P1 = c1 + cn;  // rowpair window sums
    const float Q0 = d0 + d1, Q1 = d1 + dn;

    if (t > 0) {  // emit output row t0+t-1 from rowpairs (t-1, t)
      const int orow = t0 + t - 1;
      if (orow < OUT_H) {  // only skips strip 15's phantom row 511
        const float inv = 1.0f / 16.0f;
        const float s0 = Pp0 + P0, s1 = Pp1 + P1;
        const float q0 = Qp0 + Q0, q1 = Qp1 + Q1;
        const float m0 = s0 * inv, m1 = s1 * inv;
        const float v0 = fmaxf(fmaf(-m0, m0, q0 * inv), 0.0f);
        const float v1 = fmaxf(fmaf(-m1, m1, q1 * inv), 0.0f);
        float* op = dst + (size_t)orow * OUT_W;
        op[0] = sqrtf(v0);              // out rows only 4B-aligned ->
        if (has_o1) op[1] = sqrtf(v1);  // two dword stores, both dense
      }
    }

    Pp0 = P0; Pp1 = P1; Qp0 = Q0; Qp1 = Q1;
  }
}

extern "C" void kernel_launch(void* const* d_in, const int* in_sizes, int n_in,
                              void* d_out, int out_size, void* d_ws,
                              size_t ws_size, hipStream_t stream) {
  const float* x = (const float*)d_in[0];
  float* out = (float*)d_out;

  dim3 block(256, 1, 1);
  dim3 grid(STRIPS, 64, 1);  // 16 row-strips x 64 images = 1024 blocks
  stdpool_kernel<<<grid, block, 0, stream>>>(x, out);
}